// Round 1
// 159.456 us; speedup vs baseline: 1.2100x; 1.2100x over previous
//
#include <hip/hip_runtime.h>

#define NCH   256
#define NPROT 320
#define HW    16384      // 128*128
#define TAU   20.0f
#define EPSN  1e-4f

typedef _Float16 half8 __attribute__((ext_vector_type(8)));
typedef float    f32x4 __attribute__((ext_vector_type(4)));

// ---------------------------------------------------------------------------
// Kernel 1a: avg-pool sup_x (5,256,128,128) over 16x16 cells -> praw[p][c]
// (unchanged from verified baseline)
// ---------------------------------------------------------------------------
__global__ __launch_bounds__(256) void k_pool(const float* __restrict__ sup_x,
                                              float* __restrict__ praw) {
    int b = blockIdx.x;            // s*256 + c
    int t = threadIdx.x;
    const float4* plane = (const float4*)(sup_x + (size_t)b * HW);
    float rsum[8];
    #pragma unroll
    for (int r = 0; r < 8; ++r) rsum[r] = 0.f;
    #pragma unroll
    for (int i = 0; i < 16; ++i) {
        float4 v = plane[i * 256 + t];
        rsum[i >> 1] += v.x + v.y + v.z + v.w;
    }
    __shared__ float part[8][256];
    #pragma unroll
    for (int r = 0; r < 8; ++r) part[r][t] = rsum[r];
    __syncthreads();
    int R  = t >> 5;
    int cw = t & 31;
    float s = 0.f;
    #pragma unroll
    for (int a = 0; a < 8; ++a) s += part[R][a * 32 + cw];
    s += __shfl_xor(s, 1);
    s += __shfl_xor(s, 2);
    if ((t & 3) == 0) {
        int shot = b >> 8, c = b & 255;
        int p = shot * 64 + R * 8 + (cw >> 2);
        praw[(size_t)p * NCH + c] = s * (1.0f / 256.0f);
    }
}

// ---------------------------------------------------------------------------
// Kernel 1b: per-proto center + safe-normalize, then emit fp16 hi/lo split in
// B-fragment layout for mfma_f32_16x16x32_f16:
//   frag slot (g=k>>3 within 32-k block, j=k&7) for proto n lives at
//   PT[( (k>>3)*320 + n )*8 + (k&7)]  -> one contiguous half8 per lane.
// Split: p = hi + lo/2048, hi = fp16(p), lo = fp16((p-hi)*2048).
// ---------------------------------------------------------------------------
__device__ __forceinline__ float block_sum256(float x, float* ws4, int t) {
    #pragma unroll
    for (int o = 1; o < 64; o <<= 1) x += __shfl_xor(x, o);
    if ((t & 63) == 0) ws4[t >> 6] = x;
    __syncthreads();
    float r = ws4[0] + ws4[1] + ws4[2] + ws4[3];
    __syncthreads();
    return r;
}

__global__ __launch_bounds__(256) void k_norm(const float* __restrict__ praw,
                                              _Float16* __restrict__ PTh,
                                              _Float16* __restrict__ PTl) {
    int p = blockIdx.x;
    int c = threadIdx.x;
    __shared__ float ws4[4];
    float v = praw[p * NCH + c];
    float mean = block_sum256(v, ws4, c) * (1.0f / 256.0f);
    float cen = v - mean;
    float n2 = block_sum256(cen * cen, ws4, c);
    float inv = 1.0f / fmaxf(sqrtf(n2), EPSN);
    float pn = cen * inv;
    _Float16 hi = (_Float16)pn;
    float lo = (pn - (float)hi) * 2048.0f;
    size_t idx = ((size_t)(c >> 3) * NPROT + p) * 8 + (c & 7);
    PTh[idx] = hi;
    PTl[idx] = (_Float16)lo;
}

// ---------------------------------------------------------------------------
// Kernel 2: MFMA GEMM (32 px x 320 protos x K=256) + softmax epilogue.
//  - stage 32x256 fp32 tile (verified staging), per-pixel mean/invn
//  - normalize + fp16 hi/lo split into XOR-swizzled LDS (T2: byte^=(row&7)<<4,
//    else [32][256] fp16 rows are a 16-way bank conflict on ds_read_b128)
//  - 4 waves x (2 m-tiles x 5 n-tiles) of 16x16x32_f16; 3 products/tile:
//    acc1 += qh*ph ; acc2 += qh*pl + ql*ph ; d = TAU*(acc1 + acc2/2048)
//  - D layout (m89/m91): pixel = mt*16 + (lane>>4)*4 + reg, proto col = lane&15
//  - epilogue: per-pixel max/argmax/S/T via shfl over the 16 fragment columns,
//    then a 4-wave LDS merge (protos are wave-disjoint ascending -> first-max
//    tie semantics match jnp.argmax).
// ---------------------------------------------------------------------------
__global__ __launch_bounds__(256, 2) void k_main(const float* __restrict__ qry,
                                                 const _Float16* __restrict__ PTh,
                                                 const _Float16* __restrict__ PTl,
                                                 float* __restrict__ out) {
    __shared__ __align__(16) float qlds[32 * 260];     // 33,280 B fp32 staging
    __shared__ float red[512];
    __shared__ __align__(16) _Float16 Ah[32 * 256];    // 16 KB, swizzled
    __shared__ __align__(16) _Float16 Al[32 * 256];    // 16 KB, swizzled
    __shared__ float meanv[32], invnv[32];
    __shared__ float Mw[4][32], Sw[4][32], Tw[4][32], Iw[4][32];
    int t = threadIdx.x;
    int pixbase = blockIdx.x * 32;

    // ---- stage 32 pixels x 256 channels (coalesced float4 over pixel dim) ----
    {
        int f4 = t & 7;
        int c0 = t >> 3;
        #pragma unroll
        for (int i = 0; i < 8; ++i) {
            int c = c0 + 32 * i;
            float4 v = *(const float4*)(qry + (size_t)c * HW + pixbase + f4 * 4);
            int px = f4 * 4;
            qlds[(px + 0) * 260 + c] = v.x;
            qlds[(px + 1) * 260 + c] = v.y;
            qlds[(px + 2) * 260 + c] = v.z;
            qlds[(px + 3) * 260 + c] = v.w;
        }
    }
    __syncthreads();

    // ---- per-pixel mean and inverse safe-norm ----
    {
        int pix = t & 31, sub = t >> 5;
        float s1 = 0.f, s2 = 0.f;
        #pragma unroll
        for (int j = 0; j < 32; ++j) {
            float q = qlds[pix * 260 + sub * 32 + j];
            s1 += q; s2 += q * q;
        }
        red[sub * 32 + pix] = s1;
        red[256 + sub * 32 + pix] = s2;
    }
    __syncthreads();
    if (t < 32) {
        float s1 = 0.f, s2 = 0.f;
        #pragma unroll
        for (int j = 0; j < 8; ++j) { s1 += red[j * 32 + t]; s2 += red[256 + j * 32 + t]; }
        float mean = s1 * (1.0f / 256.0f);
        float n2 = fmaxf(s2 - s1 * mean, 0.f);
        meanv[t] = mean;
        invnv[t] = 1.0f / fmaxf(sqrtf(n2), EPSN);
    }
    __syncthreads();

    // ---- normalize + fp16 hi/lo split into swizzled A-tiles (one pass) ----
    {
        int px = t >> 3, g = t & 7;
        float mean = meanv[px], invn = invnv[px];
        #pragma unroll
        for (int c8 = 0; c8 < 4; ++c8) {
            int k0 = g * 32 + c8 * 8;
            const float* src = &qlds[px * 260 + k0];
            half8 hv, lv;
            #pragma unroll
            for (int j = 0; j < 8; ++j) {
                float qn = (src[j] - mean) * invn;
                _Float16 h = (_Float16)qn;
                hv[j] = h;
                lv[j] = (_Float16)((qn - (float)h) * 2048.0f);
            }
            int off = px * 512 + ((k0 * 2) ^ ((px & 7) << 4));
            *(half8*)((char*)Ah + off) = hv;
            *(half8*)((char*)Al + off) = lv;
        }
    }
    __syncthreads();

    // ---- MFMA main loop: wave w owns protos [w*80, w*80+80) ----
    int lane = t & 63, w = t >> 6;
    int col = lane & 15, g4 = lane >> 4;

    f32x4 acc1[2][5], acc2[2][5];
    #pragma unroll
    for (int mt = 0; mt < 2; ++mt)
        #pragma unroll
        for (int nt = 0; nt < 5; ++nt) {
            acc1[mt][nt] = (f32x4){0.f, 0.f, 0.f, 0.f};
            acc2[mt][nt] = (f32x4){0.f, 0.f, 0.f, 0.f};
        }

    {
        const half8* BH = (const half8*)PTh;
        const half8* BL = (const half8*)PTl;
        int nb = w * 80 + col;
        int aswz = (col & 7) << 4;
        const char* AhB = (const char*)Ah + col * 512;
        const char* AlB = (const char*)Al + col * 512;
        #pragma unroll
        for (int kb = 0; kb < 8; ++kb) {
            int rowb = (kb * 4 + g4) * 320 + nb;
            half8 bh[5], bl[5];
            #pragma unroll
            for (int nt = 0; nt < 5; ++nt) {
                bh[nt] = BH[rowb + nt * 16];
                bl[nt] = BL[rowb + nt * 16];
            }
            int koff = (kb * 64 + g4 * 16) ^ aswz;
            half8 ah0 = *(const half8*)(AhB + koff);
            half8 ah1 = *(const half8*)(AhB + koff + 8192);
            half8 al0 = *(const half8*)(AlB + koff);
            half8 al1 = *(const half8*)(AlB + koff + 8192);
            #pragma unroll
            for (int nt = 0; nt < 5; ++nt) {
                acc1[0][nt] = __builtin_amdgcn_mfma_f32_16x16x32_f16(ah0, bh[nt], acc1[0][nt], 0, 0, 0);
                acc1[1][nt] = __builtin_amdgcn_mfma_f32_16x16x32_f16(ah1, bh[nt], acc1[1][nt], 0, 0, 0);
                acc2[0][nt] = __builtin_amdgcn_mfma_f32_16x16x32_f16(ah0, bl[nt], acc2[0][nt], 0, 0, 0);
                acc2[0][nt] = __builtin_amdgcn_mfma_f32_16x16x32_f16(al0, bh[nt], acc2[0][nt], 0, 0, 0);
                acc2[1][nt] = __builtin_amdgcn_mfma_f32_16x16x32_f16(ah1, bl[nt], acc2[1][nt], 0, 0, 0);
                acc2[1][nt] = __builtin_amdgcn_mfma_f32_16x16x32_f16(al1, bh[nt], acc2[1][nt], 0, 0, 0);
            }
        }
    }

    // ---- softmax partials per pixel over this wave's 80 protos ----
    #pragma unroll
    for (int mt = 0; mt < 2; ++mt) {
        #pragma unroll
        for (int r = 0; r < 4; ++r) {
            int pixel = mt * 16 + g4 * 4 + r;
            float dv[5];
            #pragma unroll
            for (int nt = 0; nt < 5; ++nt)
                dv[nt] = TAU * (acc1[mt][nt][r] + acc2[mt][nt][r] * (1.0f / 2048.0f));
            float gm = dv[0];
            float gi = (float)(w * 80 + col);
            #pragma unroll
            for (int nt = 1; nt < 5; ++nt)
                if (dv[nt] > gm) { gm = dv[nt]; gi = (float)(w * 80 + nt * 16 + col); }
            // reduce (max, argmax) over the 16 fragment columns (lane^1,2,4,8)
            #pragma unroll
            for (int o = 1; o < 16; o <<= 1) {
                float om = __shfl_xor(gm, o);
                float oi = __shfl_xor(gi, o);
                if (om > gm || (om == gm && oi < gi)) { gm = om; gi = oi; }
            }
            float S = 0.f, T = 0.f;
            #pragma unroll
            for (int nt = 0; nt < 5; ++nt) {
                float e = __expf(dv[nt] - gm);
                S += e;
                T = fmaf(e, dv[nt], T);
            }
            #pragma unroll
            for (int o = 1; o < 16; o <<= 1) { S += __shfl_xor(S, o); T += __shfl_xor(T, o); }
            if (col == 0) { Mw[w][pixel] = gm; Sw[w][pixel] = S; Tw[w][pixel] = T; Iw[w][pixel] = gi; }
        }
    }
    __syncthreads();

    // ---- merge 4 waves (disjoint ascending proto ranges), write out ----
    if (t < 32) {
        float gm = Mw[0][t], gi = Iw[0][t];
        #pragma unroll
        for (int k = 1; k < 4; ++k)
            if (Mw[k][t] > gm) { gm = Mw[k][t]; gi = Iw[k][t]; }
        float S = 0.f, T = 0.f;
        #pragma unroll
        for (int k = 0; k < 4; ++k) {
            float sc = __expf(Mw[k][t] - gm);
            S = fmaf(Sw[k][t], sc, S);
            T = fmaf(Tw[k][t], sc, T);
        }
        out[pixbase + t] = T / S;           // pred_grid
        out[HW + pixbase + t] = gi;         // debug_assign
    }
}

extern "C" void kernel_launch(void* const* d_in, const int* in_sizes, int n_in,
                              void* d_out, int out_size, void* d_ws, size_t ws_size,
                              hipStream_t stream) {
    const float* qry   = (const float*)d_in[0];   // (1,1,256,128,128)
    const float* sup_x = (const float*)d_in[1];   // (1,5,1,256,128,128)
    float* out = (float*)d_out;                   // 16384 pred + 16384 assign

    float* praw   = (float*)d_ws;                        // 320*256 fp32
    _Float16* PTh = (_Float16*)(praw + NPROT * NCH);     // 320*256 fp16 (frag layout)
    _Float16* PTl = PTh + NPROT * NCH;                   // 320*256 fp16 (frag layout)

    k_pool<<<5 * 256, 256, 0, stream>>>(sup_x, praw);
    k_norm<<<NPROT, 256, 0, stream>>>(praw, PTh, PTl);
    k_main<<<HW / 32, 256, 0, stream>>>(qry, PTh, PTl, out);
}